// Round 2
// 496.308 us; speedup vs baseline: 1.1026x; 1.1026x over previous
//
#include <hip/hip_runtime.h>

typedef short short8 __attribute__((ext_vector_type(8)));
typedef float floatx4 __attribute__((ext_vector_type(4)));

#define BB   8
#define CIN  16
#define COUT 32
#define DD   64
#define NUM_W (CIN * COUT * 27)   // 13824
#define NUM_P (NUM_W + COUT)      // 13856
#define KPAD  448                 // 28 taps * 16 ci (tap 27 = zeros)

// ws layout (floats): [0,64) h1 (8x8); [64,320) bias (8x32);
// [320, ...) A_bf16 as shorts: 8*32*448 shorts = 229376 B. Total ~231 KB.

__device__ __forceinline__ short f2bf(float f) {
    union { float f; unsigned u; } v; v.f = f;
    unsigned r = v.u + 0x7FFF + ((v.u >> 16) & 1);   // RNE
    return (short)(r >> 16);
}

// pack bf16(lo) | bf16(hi)<<16, both RNE — identical numerics to f2bf
__device__ __forceinline__ unsigned pack2bf(float lo, float hi) {
    union { float f; unsigned u; } a, b; a.f = lo; b.f = hi;
    unsigned ra = a.u + 0x7FFF + ((a.u >> 16) & 1);
    unsigned rb = b.u + 0x7FFF + ((b.u >> 16) & 1);
    return (ra >> 16) | (rb & 0xFFFF0000u);
}

// LDS bank-conflict swizzle: XOR bits 4-6 of the byte address with bits 7-9.
// Bijective per 128B window (buffer = 38016 B = 297 * 128B exactly).
// Preserves 16B alignment for b128 reads and 4B alignment for b32 writes.
__device__ __forceinline__ int swz(int byte) {
    return byte ^ (((byte >> 7) & 7) << 4);
}

__global__ void hyper_kernel(const float* __restrict__ features,
                             const float* __restrict__ fc0_w,
                             const float* __restrict__ fc0_b,
                             const float* __restrict__ a0,
                             const float* __restrict__ fc1_w,
                             const float* __restrict__ fc1_b,
                             const float* __restrict__ a1,
                             const float* __restrict__ wg_w,
                             const float* __restrict__ wg_b,
                             float* __restrict__ h1out,
                             float* __restrict__ biasout) {
    __shared__ float h0[8][16];
    __shared__ float h1s[8][8];
    const int t = threadIdx.x;  // 256
    if (t < 128) {
        const int b = t >> 4, i = t & 15;
        float s = fc0_b[i];
        #pragma unroll
        for (int j = 0; j < 10; ++j) s += features[b * 10 + j] * fc0_w[i * 10 + j];
        const float a = a0[0];
        h0[b][i] = (s >= 0.f) ? s : a * s;
    }
    __syncthreads();
    if (t < 64) {
        const int b = t >> 3, i = t & 7;
        float s = fc1_b[i];
        #pragma unroll
        for (int j = 0; j < 16; ++j) s += h0[b][j] * fc1_w[i * 16 + j];
        const float a = a1[0];
        const float r = (s >= 0.f) ? s : a * s;
        h1s[b][i] = r;
        h1out[b * 8 + i] = r;
    }
    __syncthreads();
    {   // biases: 256 threads = 8 b x 32 co
        const int b = t >> 5, co = t & 31;
        const int p = NUM_W + co;
        float s = wg_b[p];
        #pragma unroll
        for (int j = 0; j < 8; ++j) s += h1s[b][j] * wg_w[p * 8 + j];
        biasout[b * 32 + co] = s;
    }
}

// A_bf16[b][co][k], k = tap*16 + ci, tap = kd*9+kh*3+kw, zero for tap==27
// Thread map: tap fastest -> adjacent lanes read adjacent wg_w rows (coalesced).
__global__ void wgen_kernel(const float* __restrict__ h1,
                            const float* __restrict__ wg_w,
                            const float* __restrict__ wg_b,
                            short* __restrict__ A) {
    const int b  = blockIdx.y;
    const int id = blockIdx.x * 256 + threadIdx.x;  // [0, 32*16*28)
    const int tap  = id % 28;
    const int rest = id / 28;        // co*16 + ci
    const int ci   = rest & 15;
    const int co   = rest >> 4;
    float val = 0.f;
    if (tap < 27) {
        const int p = co * 432 + ci * 27 + tap;
        float s = wg_b[p];
        #pragma unroll
        for (int j = 0; j < 8; ++j) s += h1[b * 8 + j] * wg_w[p * 8 + j];
        val = s;
    }
    A[(b * 32 + co) * KPAD + tap * 16 + ci] = f2bf(val);
}

// Implicit-GEMM conv via MFMA 16x16x32 bf16.
// Block = 256 thr = 4 waves; tile = (b, d, h0..h0+3, w 0..63).
// LDS x-patch: [dz 3][hz 6][wz 66][ci 16] bf16, XOR-swizzled (see swz()).
__global__ __launch_bounds__(256, 2) void conv_mfma_kernel(
        const float* __restrict__ x,
        const short* __restrict__ A,
        const float* __restrict__ bias,
        float* __restrict__ out) {
    __shared__ uint4 xs4[2376];            // 38016 B = 3*6*66*16 bf16
    char* xsb = (char*)xs4;

    const int t    = threadIdx.x;
    const int lane = t & 63;
    const int wave = t >> 6;
    const int n16  = lane & 15;
    const int q    = lane >> 4;

    // XCD-aware block swizzle: each XCD gets a contiguous 1024-block chunk of
    // the original (b,d,h0) ordering -> halo rows + per-sample A stay L2-hot.
    const int lin = (blockIdx.z * 64 + blockIdx.y) * 16 + blockIdx.x;  // 0..8191
    const int o   = (lin & 7) * 1024 + (lin >> 3);                     // bijective
    const int h0  = (o & 15) * 4;
    const int d   = (o >> 4) & 63;
    const int b   = o >> 10;

    // ---- preload all A-fragments (L2-hot, 28 KB per sample) ----
    short8 afrag[14][2];
    const short* Ab = A + (size_t)(b * 32) * KPAD;
    #pragma unroll
    for (int c = 0; c < 14; ++c)
        #pragma unroll
        for (int mt = 0; mt < 2; ++mt) {
            const int co = mt * 16 + n16;          // A: m = lane&15
            afrag[c][mt] = *(const short8*)(Ab + co * KPAD + c * 32 + q * 8);
        }

    // ---- zero LDS (halo/pad); swizzle-invariant since we zero everything ----
    const uint4 z4 = {0u, 0u, 0u, 0u};
    #pragma unroll
    for (int i = 0; i < 10; ++i) {
        const int idx = t + i * 256;
        if (idx < 2376) xs4[idx] = z4;
    }
    __syncthreads();

    // ---- stage x -> LDS bf16 (paired-ci b32 writes, swizzled, conflict-free) ----
    // Thread covers (ci-pair cp, w-chunk n16); 9 rows each. Branch wave-uniform.
    const int tid16 = wave * 4 + q;      // 0..15
    const int cp    = tid16 & 7;         // ci = 2*cp, 2*cp+1
    const int rhalf = tid16 >> 3;        // rows 0..8 / 9..17
    const int w4    = n16 * 4;
    #pragma unroll
    for (int i = 0; i < 9; ++i) {
        const int rowl = rhalf * 9 + i;              // 0..17 = dz*6+hz
        const int dz = rowl / 6, hz = rowl % 6;
        const int zd = d + dz - 1;
        const int zh = h0 + hz - 1;
        if (zd >= 0 && zd < DD && zh >= 0 && zh < DD) {
            const size_t gbase =
                (((size_t)(b * CIN + 2 * cp) * DD + zd) * DD + zh) * DD + w4;
            const float4 v0 = *(const float4*)(x + gbase);
            const float4 v1 = *(const float4*)(x + gbase + (size_t)DD * DD * DD);
            // byte addr of (rowl, wz=w4+1+k, ci=2cp): (rowl*66+wz)*32 + 4*cp
            const int rb = (rowl * 66 + (w4 + 1)) * 32 + 4 * cp;
            *(unsigned*)(xsb + swz(rb))      = pack2bf(v0.x, v1.x);
            *(unsigned*)(xsb + swz(rb + 32)) = pack2bf(v0.y, v1.y);
            *(unsigned*)(xsb + swz(rb + 64)) = pack2bf(v0.z, v1.z);
            *(unsigned*)(xsb + swz(rb + 96)) = pack2bf(v0.w, v1.w);
        }
    }
    __syncthreads();

    // ---- K-loop: 14 chunks x (4 n-tiles x 2 m-tiles) MFMA ----
    floatx4 acc[2][4];
    #pragma unroll
    for (int mt = 0; mt < 2; ++mt)
        #pragma unroll
        for (int nt = 0; nt < 4; ++nt) acc[mt][nt] = (floatx4){0.f, 0.f, 0.f, 0.f};

    const int ci_base2 = (q & 1) * 16;   // byte offset of ci_base
    const int qh       = q >> 1;
    #pragma unroll
    for (int c = 0; c < 14; ++c) {
        int tap = 2 * c + qh;
        if (tap > 26) tap = 26;                 // A is zero for k>=432, B value irrelevant
        const int kd = tap / 9;
        const int r  = tap - kd * 9;
        const int kh = r / 3;
        const int kw = r - kh * 3;
        const int rowb = ((kd * 6 + wave + kh) * 66 + kw) * 32 + ci_base2;  // byte
        #pragma unroll
        for (int nt = 0; nt < 4; ++nt) {
            const int byteoff = rowb + (nt * 16 + n16) * 32;
            const short8 bfrag = *(const short8*)(xsb + swz(byteoff));
            acc[0][nt] = __builtin_amdgcn_mfma_f32_16x16x32_bf16(
                             afrag[c][0], bfrag, acc[0][nt], 0, 0, 0);
            acc[1][nt] = __builtin_amdgcn_mfma_f32_16x16x32_bf16(
                             afrag[c][1], bfrag, acc[1][nt], 0, 0, 0);
        }
    }

    // ---- epilogue: C/D layout col=lane&15(w), row=q*4+reg(co) ----
    const int hh = h0 + wave;
    #pragma unroll
    for (int mt = 0; mt < 2; ++mt) {
        const floatx4 bv = *(const floatx4*)(bias + b * 32 + mt * 16 + q * 4);
        #pragma unroll
        for (int nt = 0; nt < 4; ++nt) {
            const int w = nt * 16 + n16;
            #pragma unroll
            for (int reg = 0; reg < 4; ++reg) {
                const int co = mt * 16 + q * 4 + reg;
                out[(((size_t)(b * COUT + co) * DD + d) * DD + hh) * DD + w] =
                    acc[mt][nt][reg] + bv[reg];
            }
        }
    }
}

extern "C" void kernel_launch(void* const* d_in, const int* in_sizes, int n_in,
                              void* d_out, int out_size, void* d_ws, size_t ws_size,
                              hipStream_t stream) {
    const float* x        = (const float*)d_in[0];
    const float* features = (const float*)d_in[1];
    const float* fc0_w    = (const float*)d_in[2];
    const float* fc0_b    = (const float*)d_in[3];
    const float* a0       = (const float*)d_in[4];
    const float* fc1_w    = (const float*)d_in[5];
    const float* fc1_b    = (const float*)d_in[6];
    const float* a1       = (const float*)d_in[7];
    const float* wg_w     = (const float*)d_in[8];
    const float* wg_b     = (const float*)d_in[9];

    float* ws    = (float*)d_ws;
    float* h1    = ws;                // 64 floats
    float* biasp = ws + 64;           // 256 floats
    short* A     = (short*)(ws + 320);  // 8*32*448 shorts

    hyper_kernel<<<1, 256, 0, stream>>>(features, fc0_w, fc0_b, a0,
                                        fc1_w, fc1_b, a1, wg_w, wg_b, h1, biasp);
    wgen_kernel<<<dim3(56, BB), 256, 0, stream>>>(h1, wg_w, wg_b, A);
    conv_mfma_kernel<<<dim3(16, DD, BB), 256, 0, stream>>>(x, A, biasp, (float*)d_out);
}